// Round 3
// baseline (99.104 us; speedup 1.0000x reference)
//
#include <hip/hip_runtime.h>

#define AS1 __attribute__((address_space(1)))
#define AS3 __attribute__((address_space(3)))

typedef __bf16 bf16x8 __attribute__((ext_vector_type(8)));
typedef float f32x4 __attribute__((ext_vector_type(4)));

static constexpr int C = 768;
static constexpr int NB = 128;    // N1 == N2
static constexpr int S  = 256;    // W*H
static constexpr int XY_ELEMS  = NB * NB * S;  // 4194304
static constexpr int XSQ_ELEMS = NB * S;       // 32768

// ---------------------------------------------------------------------------
// Pass 1: transpose [n][c][s] fp32 -> [s][n][c] bf16 + fused square-mean.
// grid: 2048 blocks = (tensor, n, s-tile of 64, c-half of 384), 256 threads.
// 12 chunks of 32c x 64s, double-buffered LDS (17.4 KB -> 8 blocks/CU),
// ONE raw s_barrier per chunk draining lgkmcnt only; prefetch issued BEFORE
// the LDS write so the vmcnt stall overlaps the issue.
// Square-means: per-block partial (c-half) -> fp32 atomicAdd (2 commutative
// adds per element = deterministic) onto memset-zeroed xx/yy region.
// ---------------------------------------------------------------------------
__global__ __launch_bounds__(256) void pass1(const float* __restrict__ x,
                                             const float* __restrict__ y,
                                             unsigned short* __restrict__ xb,
                                             unsigned short* __restrict__ yb,
                                             float* __restrict__ out) {
  const int b      = blockIdx.x;
  const int tensor = b >> 10;         // 0 = x, 1 = y
  const int local  = b & 1023;
  const int n      = local >> 3;      // 0..127
  const int st     = (local >> 1) & 3;// s-tile of 64
  const int ch2    = local & 1;       // c-half (0: c<384, 1: c>=384)

  const float*    src = tensor ? y  : x;
  unsigned short* dst = tensor ? yb : xb;
  float*          sqo = out + XY_ELEMS + tensor * XSQ_ELEMS;

  __shared__ float tile[2][32 * 68];   // 2 x 8704 B = 17408 B

  const int t  = threadIdx.x;
  const int cl = t >> 4;               // 0..15 (load-side c row)
  const int s4 = (t & 15) * 4;         // 0..60 (load-side s offset)
  const int sl = t >> 2;               // 0..63 (store-side s row)
  const int cq = t & 3;                // 0..3  (store-side c group of 8)

  const float* srcn =
      src + (size_t)n * (C * S) + (size_t)(ch2 * 384) * S + st * 64;
  unsigned short* dstn =
      dst + ((size_t)(st * 64 + sl) * NB + n) * C + ch2 * 384;

  f32x4 acc = {0.f, 0.f, 0.f, 0.f};
  f32x4 c0r, c1r, n0r, n1r;

  // prologue: chunk 0 (nontemporal: don't evict bf16 ws from L3)
  c0r = __builtin_nontemporal_load(
      reinterpret_cast<const f32x4*>(srcn + (size_t)cl * S + s4));
  c1r = __builtin_nontemporal_load(
      reinterpret_cast<const f32x4*>(srcn + (size_t)(16 + cl) * S + s4));

#pragma unroll
  for (int ch = 0; ch < 12; ++ch) {
    float* tb = tile[ch & 1];

    // ---- issue prefetch FIRST (overlaps the vmcnt stall on cur)
    if (ch < 11) {
      const float* p0 = srcn + (size_t)((ch + 1) * 32 + cl) * S + s4;
      const float* p1 = srcn + (size_t)((ch + 1) * 32 + 16 + cl) * S + s4;
      n0r = __builtin_nontemporal_load(reinterpret_cast<const f32x4*>(p0));
      n1r = __builtin_nontemporal_load(reinterpret_cast<const f32x4*>(p1));
    }

    // ---- squares + vectorized LDS write (b128, swizzled)
    acc += c0r * c0r;
    acc += c1r * c1r;
    *reinterpret_cast<f32x4*>(
        &tb[cl * 68 + (s4 ^ ((((cl) >> 3) & 3) << 3))]) = c0r;
    *reinterpret_cast<f32x4*>(
        &tb[(16 + cl) * 68 + (s4 ^ ((((16 + cl) >> 3) & 3) << 3))]) = c1r;

    // ---- barrier: drain LDS writes only, NOT the prefetch vmcnt
    asm volatile("s_waitcnt lgkmcnt(0)" ::: "memory");
    __builtin_amdgcn_s_barrier();

    // ---- transposed read + bf16 cvt + 16B store (64B/line across 4 cq)
    alignas(16) unsigned short u[8];
#pragma unroll
    for (int i = 0; i < 8; ++i) {
      int c_loc = cq * 8 + i;
      float f   = tb[c_loc * 68 + (sl ^ (cq << 3))];
      unsigned fu = __float_as_uint(f);
      unsigned r  = fu + 0x7fffu + ((fu >> 16) & 1u);  // RNE
      u[i] = (unsigned short)(r >> 16);
    }
    *reinterpret_cast<uint4*>(dstn + ch * 32 + cq * 8) =
        *reinterpret_cast<const uint4*>(u);

    c0r = n0r;
    c1r = n1r;
  }

  // ---- square-mean partial reduction (reuse tile as [16][64])
  __syncthreads();
  float* part = &tile[0][0];
#pragma unroll
  for (int j = 0; j < 4; ++j) part[cl * 64 + s4 + j] = acc[j];
  __syncthreads();
  if (t < 64) {
    float ssum = 0.f;
#pragma unroll
    for (int i = 0; i < 16; ++i) ssum += part[i * 64 + t];
    atomicAdd(&sqo[n * S + st * 64 + t], ssum * (1.0f / 768.0f));
  }
}

// ---------------------------------------------------------------------------
// Pass 2: per spatial s, C_s = (1/768) * A_s * B_s^T, split into 4 quadrant
// blocks of 64x64 -> grid 1024, LDS 16 KB (4 blocks/CU co-resident so the
// global_load_lds+barrier rounds overlap across blocks). XCD swizzle keeps
// all 4 quadrants of each s and 32 consecutive s on one XCD so the
// 4B-stride-1KB output scatter merges in its L2.
// ---------------------------------------------------------------------------
__global__ __launch_bounds__(256) void pass2(const unsigned short* __restrict__ xb,
                                             const unsigned short* __restrict__ yb,
                                             float* __restrict__ out) {
  const int b     = blockIdx.x;
  const int xcd   = b & 7;
  const int loc   = b >> 3;           // 0..127
  const int s     = xcd * 32 + (loc >> 2);
  const int q     = loc & 3;
  const int n0    = (q >> 1) * 64;
  const int m0    = (q & 1) * 64;

  const unsigned short* A = xb + (size_t)s * (NB * C) + (size_t)n0 * C;
  const unsigned short* B = yb + (size_t)s * (NB * C) + (size_t)m0 * C;

  __shared__ unsigned short As[64 * 64];
  __shared__ unsigned short Bs[64 * 64];

  const int t    = threadIdx.x;
  const int lane = t & 63;
  const int w    = t >> 6;
  const int wn   = w >> 1;   // 0..1
  const int wm   = w & 1;    // 0..1

  f32x4 acc[2][2] = {};

  for (int k0 = 0; k0 < 12; ++k0) {
    // ---- stage A,B: 64 rows x 64 k bf16 each; LDS linear, source
    // pre-swizzled j ^= row&7 (rule 21: swizzle source + read, dest linear)
#pragma unroll
    for (int i = 0; i < 2; ++i) {
      int ci  = i * 256 + t;          // 0..511 = row*8 + j
      int row = ci >> 3;
      int js  = (ci & 7) ^ (row & 7);
      const unsigned short* gpA = A + row * C + k0 * 64 + js * 8;
      const unsigned short* gpB = B + row * C + k0 * 64 + js * 8;
      __builtin_amdgcn_global_load_lds((const AS1 unsigned int*)gpA,
                                       (AS3 unsigned int*)((char*)As + ci * 16),
                                       16, 0, 0);
      __builtin_amdgcn_global_load_lds((const AS1 unsigned int*)gpB,
                                       (AS3 unsigned int*)((char*)Bs + ci * 16),
                                       16, 0, 0);
    }
    __syncthreads();

#pragma unroll
    for (int ks = 0; ks < 2; ++ks) {
      bf16x8 af[2], bfr[2];
      int jg = ks * 4 + (lane >> 4);
#pragma unroll
      for (int mi = 0; mi < 2; ++mi) {
        int row = wn * 32 + mi * 16 + (lane & 15);
        af[mi] = *reinterpret_cast<const bf16x8*>(
            (char*)As + row * 128 + ((jg ^ (row & 7)) * 16));
      }
#pragma unroll
      for (int nj = 0; nj < 2; ++nj) {
        int row = wm * 32 + nj * 16 + (lane & 15);
        bfr[nj] = *reinterpret_cast<const bf16x8*>(
            (char*)Bs + row * 128 + ((jg ^ (row & 7)) * 16));
      }
#pragma unroll
      for (int mi = 0; mi < 2; ++mi)
#pragma unroll
        for (int nj = 0; nj < 2; ++nj)
          acc[mi][nj] = __builtin_amdgcn_mfma_f32_16x16x32_bf16(
              af[mi], bfr[nj], acc[mi][nj], 0, 0, 0);
    }
    __syncthreads();
  }

  // ---- epilogue: C/D layout col=lane&15, row=(lane>>4)*4+reg (m89-verified)
  const float inv = 1.0f / 768.0f;
#pragma unroll
  for (int mi = 0; mi < 2; ++mi) {
#pragma unroll
    for (int nj = 0; nj < 2; ++nj) {
#pragma unroll
      for (int r = 0; r < 4; ++r) {
        int nn = n0 + wn * 32 + mi * 16 + (lane >> 4) * 4 + r;  // x index
        int mm = m0 + wm * 32 + nj * 16 + (lane & 15);          // y index
        out[((size_t)nn * NB + mm) * S + s] = acc[mi][nj][r] * inv;
      }
    }
  }
}

extern "C" void kernel_launch(void* const* d_in, const int* in_sizes, int n_in,
                              void* d_out, int out_size, void* d_ws, size_t ws_size,
                              hipStream_t stream) {
  const float* x = (const float*)d_in[0];
  const float* y = (const float*)d_in[1];
  float* out = (float*)d_out;

  unsigned short* xb = (unsigned short*)d_ws;       // [256][128][768] bf16
  unsigned short* yb = xb + (size_t)S * NB * C;

  // zero the xx/yy region (atomicAdd accumulates into it)
  hipMemsetAsync(out + XY_ELEMS, 0, (size_t)2 * XSQ_ELEMS * sizeof(float),
                 stream);
  pass1<<<2048, 256, 0, stream>>>(x, y, xb, yb, out);
  pass2<<<1024, 256, 0, stream>>>(xb, yb, out);
}